// Round 6
// baseline (181.699 us; speedup 1.0000x reference)
//
#include <hip/hip_runtime.h>

#define Bn 64
#define Dn 128
#define Ln 512

typedef __attribute__((ext_vector_type(8))) short short8;
typedef __attribute__((ext_vector_type(4))) float f32x4;

// truncating bf16 split: x ~= hi + lo
__device__ __forceinline__ void split8(const float* xs, short8& hi, short8& lo) {
#pragma unroll
  for (int j = 0; j < 8; ++j) {
    unsigned int u = __float_as_uint(xs[j]);
    float l = xs[j] - __uint_as_float(u & 0xFFFF0000u);
    hi[j] = (short)(u >> 16);
    lo[j] = (short)(__float_as_uint(l) >> 16);
  }
}
__device__ __forceinline__ unsigned int bftr(float x) {
  return __float_as_uint(x) >> 16;
}
__device__ __forceinline__ float bf2f(unsigned int h) {
  return __uint_as_float(h << 16);
}

// ---- kx: pre-split X2 -> bf16 hi/lo images, layout [b][m][e] ----
__global__ __launch_bounds__(256) void kx(const float* __restrict__ X2,
                                          unsigned short* __restrict__ x2h,
                                          unsigned short* __restrict__ x2l) {
  int tid = blockIdx.x * 256 + threadIdx.x;  // 524288
  int ib = tid * 8;                          // ((b*512+m)*128+e)
  int e = ib & 127, m = (ib >> 7) & 511, b = tid >> 13;
  const float* src = X2 + ((size_t)m * Bn + b) * Dn + e;
  float xs[8];
  *(float4*)xs = *(const float4*)src;
  *(float4*)(xs + 4) = *(const float4*)(src + 4);
  short8 hi, lo;
  split8(xs, hi, lo);
  *(short8*)(x2h + ib) = hi;
  *(short8*)(x2l + ib) = lo;
}

// ---- kw: pre-split W_U -> frag-ordered images ----
// unit (h,dgrp,ks,comp) 512 ushorts; lane ln: d=dgrp*16+(ln&15), e=ks*32+(ln>>4)*8
__global__ __launch_bounds__(256) void kw(const float* __restrict__ WU,
                                          unsigned short* __restrict__ wimg) {
  int blk = blockIdx.x;  // 32: h = blk>>3, dgrp = blk&7
  int t = threadIdx.x, ln = t & 63, ks = t >> 6;
  int h = blk >> 3, dgrp = blk & 7;
  int d = dgrp * 16 + (ln & 15), e = ks * 32 + (ln >> 4) * 8;
  const float* src = WU + ((size_t)h * Dn + d) * Dn + e;
  float xs[8];
  *(float4*)xs = *(const float4*)src;
  *(float4*)(xs + 4) = *(const float4*)(src + 4);
  short8 hi, lo;
  split8(xs, hi, lo);
  size_t u = (size_t)(((h * 8 + dgrp) * 4 + ks) * 2) * 512 + (size_t)ln * 8;
  *(short8*)(wimg + u) = hi;
  *(short8*)(wimg + u + 512) = lo;
}

// ---- k1 fused: per (b,h,mhalf): Z=WU.X2^T -> LDS (swizzled bf16 hi/lo),
// then masked row/col maxes of S = X1 . Z^T. 512 threads, no zimg. ----
// LDS Z layout (per comp 64KB): byte = m*256 + (((d>>3)^(m&7))<<4) + (d&7)*2
__global__ __launch_bounds__(512, 2) void k1(const float* __restrict__ X1,
                                             const unsigned short* __restrict__ x2h,
                                             const unsigned short* __restrict__ x2l,
                                             const unsigned short* __restrict__ wimg,
                                             const int* __restrict__ raw1,
                                             const int* __restrict__ raw2,
                                             float* __restrict__ s1pp,
                                             float* __restrict__ s2) {
  __shared__ __align__(16) char ldsb[142336];
  char* Zh = ldsb;                         // 65536
  char* Zl = ldsb + 65536;                 // 65536
  float* m2f = (float*)(ldsb + 131072);    // 256
  float* m1f = (float*)(ldsb + 132096);    // 512
  float* cmbuf = (float*)(ldsb + 134144);  // 8*256

  int orig = blockIdx.x;
  int blk = (orig & 7) * 64 + (orig >> 3);  // XCD swizzle, 512 = 8*64
  int mhalf = blk & 1, h = (blk >> 1) & 3, b = blk >> 3;
  int bh = b * 4 + h;
  int t = threadIdx.x, ln = t & 63, wv = t >> 6;

  // masks
  if (t < 512) m1f[t] = (raw1[(size_t)t * Bn + b] == 0) ? 1.0e4f : 0.0f;
  if (t < 256) m2f[t] = (raw2[(size_t)(mhalf * 256 + t) * Bn + b] == 0) ? 1.0e4f : 0.0f;

  // ---- Z phase: wave wv owns d-slice [wv*16, wv*16+16), all 256 m ----
  {
    // A3 = WU frags (resident): 4 ks x 2 comp
    short8 a3h[4], a3l[4];
#pragma unroll
    for (int ks = 0; ks < 4; ++ks) {
      size_t u = (size_t)(((h * 8 + wv) * 4 + ks) * 2) * 512 + (size_t)ln * 8;
      a3h[ks] = *(const short8*)(wimg + u);
      a3l[ks] = *(const short8*)(wimg + u + 512);
    }
    f32x4 zacc[16];
    const f32x4 fz = {0.f, 0.f, 0.f, 0.f};
#pragma unroll
    for (int i = 0; i < 16; ++i) zacc[i] = fz;

    size_t x2base = ((size_t)(b * 512 + mhalf * 256 + (ln & 15)) * Dn) + (ln >> 4) * 8;
#pragma unroll
    for (int ks = 0; ks < 4; ++ks) {
#pragma unroll
      for (int mg = 0; mg < 16; ++mg) {
        size_t a = x2base + (size_t)mg * 16 * Dn + ks * 32;
        short8 bhf = *(const short8*)(x2h + a);
        short8 blf = *(const short8*)(x2l + a);
        zacc[mg] = __builtin_amdgcn_mfma_f32_16x16x32_bf16(a3h[ks], bhf, zacc[mg], 0, 0, 0);
        zacc[mg] = __builtin_amdgcn_mfma_f32_16x16x32_bf16(a3h[ks], blf, zacc[mg], 0, 0, 0);
        zacc[mg] = __builtin_amdgcn_mfma_f32_16x16x32_bf16(a3l[ks], bhf, zacc[mg], 0, 0, 0);
      }
    }
    // write Z to LDS: C layout col=m=ln&15(+mg*16), row=d=wv*16+(ln>>4)*4+j
    int d0 = wv * 16 + (ln >> 4) * 4;
#pragma unroll
    for (int mg = 0; mg < 16; ++mg) {
      int mloc = mg * 16 + (ln & 15);
      unsigned int h0 = bftr(zacc[mg][0]), h1 = bftr(zacc[mg][1]);
      unsigned int h2 = bftr(zacc[mg][2]), h3 = bftr(zacc[mg][3]);
      uint2 hw;
      hw.x = h0 | (h1 << 16);
      hw.y = h2 | (h3 << 16);
      unsigned int l0 = bftr(zacc[mg][0] - bf2f(h0)), l1 = bftr(zacc[mg][1] - bf2f(h1));
      unsigned int l2 = bftr(zacc[mg][2] - bf2f(h2)), l3 = bftr(zacc[mg][3] - bf2f(h3));
      uint2 lw;
      lw.x = l0 | (l1 << 16);
      lw.y = l2 | (l3 << 16);
      int ad = mloc * 256 + ((((d0 >> 3) ^ (mloc & 7))) << 4) + (d0 & 7) * 2;
      *(uint2*)(Zh + ad) = hw;
      *(uint2*)(Zl + ad) = lw;
    }
  }
  __syncthreads();

  // ---- S phase: wave wv owns rows [wv*64, +64); cols = 256 of mhalf ----
  int R0 = wv * 64;
  short8 ahf[4][4], alf[4][4];
  {
    int eo = (ln >> 4) * 8;
#pragma unroll
    for (int mr = 0; mr < 4; ++mr) {
      const float* rsrc = X1 + ((size_t)(R0 + mr * 16 + (ln & 15)) * Bn + b) * Dn + eo;
#pragma unroll
      for (int ks = 0; ks < 4; ++ks) {
        float xs[8];
        *(float4*)xs = *(const float4*)(rsrc + ks * 32);
        *(float4*)(xs + 4) = *(const float4*)(rsrc + ks * 32 + 4);
        split8(xs, ahf[mr][ks], alf[mr][ks]);
      }
    }
  }
  float msub1[16];
#pragma unroll
  for (int mr = 0; mr < 4; ++mr)
#pragma unroll
    for (int j = 0; j < 4; ++j) msub1[mr * 4 + j] = m1f[R0 + mr * 16 + (ln >> 4) * 4 + j];

  float rmrun[16];
#pragma unroll
  for (int i = 0; i < 16; ++i) rmrun[i] = -3.0e38f;

  const f32x4 fz = {0.f, 0.f, 0.f, 0.f};
  int mlocL = ln & 15;
  int dbase = (ln >> 4) * 8;
#pragma unroll
  for (int cg = 0; cg < 16; ++cg) {
    int mloc = cg * 16 + mlocL;
    float ms2 = m2f[mloc];
    f32x4 acc[4];
#pragma unroll
    for (int i = 0; i < 4; ++i) acc[i] = fz;
#pragma unroll
    for (int ks = 0; ks < 4; ++ks) {
      int dd = ks * 32 + dbase;
      int ad = mloc * 256 + ((((dd >> 3) ^ (mloc & 7))) << 4);
      short8 bhf = *(const short8*)(Zh + ad);
      short8 blf = *(const short8*)(Zl + ad);
#pragma unroll
      for (int mr = 0; mr < 4; ++mr) {
        acc[mr] = __builtin_amdgcn_mfma_f32_16x16x32_bf16(ahf[mr][ks], bhf, acc[mr], 0, 0, 0);
        acc[mr] = __builtin_amdgcn_mfma_f32_16x16x32_bf16(ahf[mr][ks], blf, acc[mr], 0, 0, 0);
        acc[mr] = __builtin_amdgcn_mfma_f32_16x16x32_bf16(alf[mr][ks], bhf, acc[mr], 0, 0, 0);
      }
    }
    // rowmax partials (mask2 per col), defer cross-lane
#pragma unroll
    for (int mr = 0; mr < 4; ++mr)
#pragma unroll
      for (int j = 0; j < 4; ++j)
        rmrun[mr * 4 + j] = fmaxf(rmrun[mr * 4 + j], acc[mr][j] - ms2);
    // colmax over this wave's 64 rows (mask1)
    float v = -3.0e38f;
#pragma unroll
    for (int mr = 0; mr < 4; ++mr)
#pragma unroll
      for (int j = 0; j < 4; ++j) v = fmaxf(v, acc[mr][j] - msub1[mr * 4 + j]);
    v = fmaxf(v, __shfl_xor(v, 16));
    v = fmaxf(v, __shfl_xor(v, 32));
    if (ln < 16) cmbuf[wv * 256 + cg * 16 + ln] = v;
  }

  // rowmax cross-lane + write (complete over this mhalf)
#pragma unroll
  for (int off = 1; off < 16; off <<= 1)
#pragma unroll
    for (int i = 0; i < 16; ++i) rmrun[i] = fmaxf(rmrun[i], __shfl_xor(rmrun[i], off));
  if ((ln & 15) == 0) {
    float* dst = s1pp + ((size_t)bh * 2 + mhalf) * 512 + R0 + (ln >> 4) * 4;
#pragma unroll
    for (int mr = 0; mr < 4; ++mr)
#pragma unroll
      for (int j = 0; j < 4; ++j) dst[mr * 16 + j] = rmrun[mr * 4 + j];
  }
  __syncthreads();
  if (t < 256) {
    float v = cmbuf[t];
#pragma unroll
    for (int w = 1; w < 8; ++w) v = fmaxf(v, cmbuf[w * 256 + t]);
    s2[(size_t)bh * 512 + mhalf * 256 + t] = v;  // complete colmax
  }
}

// ---- k2: (side,b,lq): wave h = tanh+softmax; partial readout over l-quarter
__global__ __launch_bounds__(256) void k2(const float* __restrict__ s1pp,
                                          const float* __restrict__ s2,
                                          const float* __restrict__ X1,
                                          const float* __restrict__ X2,
                                          float* __restrict__ out,
                                          float* __restrict__ rws4) {
  __shared__ float aL[4][512];
  __shared__ f32x4 redv[4][8][32];
  int blk = blockIdx.x;  // 512
  int side = blk >> 8, b = (blk >> 2) & 63, lq = blk & 3;
  int t = threadIdx.x, ln = t & 63, h = t >> 6;
  int bh = b * 4 + h;
  int base = ln * 8;

  float vals[8];
  if (side == 0) {
    const float* p0 = s1pp + ((size_t)bh * 2) * 512 + base;
#pragma unroll
    for (int q = 0; q < 8; q += 4) {
      float4 va = *(const float4*)(p0 + q);
      float4 vb = *(const float4*)(p0 + 512 + q);
      vals[q + 0] = fmaxf(va.x, vb.x);
      vals[q + 1] = fmaxf(va.y, vb.y);
      vals[q + 2] = fmaxf(va.z, vb.z);
      vals[q + 3] = fmaxf(va.w, vb.w);
    }
  } else {
    const float* p = s2 + (size_t)bh * 512 + base;
#pragma unroll
    for (int q = 0; q < 8; q += 4) {
      float4 v = *(const float4*)(p + q);
      vals[q + 0] = v.x;
      vals[q + 1] = v.y;
      vals[q + 2] = v.z;
      vals[q + 3] = v.w;
    }
  }
#pragma unroll
  for (int q = 0; q < 8; ++q) vals[q] = tanhf(vals[q]);
  float mx = vals[0];
#pragma unroll
  for (int q = 1; q < 8; ++q) mx = fmaxf(mx, vals[q]);
#pragma unroll
  for (int off = 1; off < 64; off <<= 1) mx = fmaxf(mx, __shfl_xor(mx, off));
  float s = 0.0f;
#pragma unroll
  for (int q = 0; q < 8; ++q) {
    vals[q] = expf(vals[q] - mx);
    s += vals[q];
  }
#pragma unroll
  for (int off = 1; off < 64; off <<= 1) s += __shfl_xor(s, off);
  float inv = 1.0f / s;
#pragma unroll
  for (int q = 0; q < 8; ++q) vals[q] *= inv;

  if (lq == 0) {
    int aoff = (side == 0 ? 16384 : 147456) + bh * 512 + base;
    *(float4*)(out + aoff) = make_float4(vals[0], vals[1], vals[2], vals[3]);
    *(float4*)(out + aoff + 4) = make_float4(vals[4], vals[5], vals[6], vals[7]);
  }
  *(float4*)(&aL[h][base]) = make_float4(vals[0], vals[1], vals[2], vals[3]);
  *(float4*)(&aL[h][base + 4]) = make_float4(vals[4], vals[5], vals[6], vals[7]);
  __syncthreads();

  // partial readout over l in [lq*128, +128)
  const float4* X4 = (const float4*)(side == 0 ? X1 : X2);
  int q = t & 31, lg = t >> 5;
  f32x4 av[4];
  const f32x4 fz = {0.f, 0.f, 0.f, 0.f};
#pragma unroll
  for (int hh = 0; hh < 4; ++hh) av[hh] = fz;
#pragma unroll 4
  for (int l = lq * 128 + lg; l < lq * 128 + 128; l += 8) {
    float4 xv = X4[((size_t)l * Bn + b) * 32 + q];
#pragma unroll
    for (int hh = 0; hh < 4; ++hh) {
      float w = aL[hh][l];
      av[hh][0] += w * xv.x;
      av[hh][1] += w * xv.y;
      av[hh][2] += w * xv.z;
      av[hh][3] += w * xv.w;
    }
  }
#pragma unroll
  for (int hh = 0; hh < 4; ++hh) redv[hh][lg][q] = av[hh];
  __syncthreads();
  if (t < 128) {
    int d = t;
#pragma unroll
    for (int hh = 0; hh < 4; ++hh) {
      float s2v = 0.0f;
#pragma unroll
      for (int g = 0; g < 8; ++g) s2v += ((const float*)&redv[hh][g][d >> 2])[d & 3];
      rws4[(((size_t)(side * 64 + b) * 4 + hh) * 4 + lq) * 128 + d] = s2v;
    }
  }
}

// ---- k3: combine hops (sums lq partials) ----
__global__ __launch_bounds__(128) void k3(const float* __restrict__ rws4,
                                          const float* __restrict__ Wipm,
                                          float* __restrict__ out) {
  int b = blockIdx.x, t = threadIdx.x;  // t = d
  __shared__ float r2l[4][128];
  __shared__ float tsum[2][4];
  float r1h[4], r2h[4];
#pragma unroll
  for (int h = 0; h < 4; ++h) {
    float a0 = 0.f, a1 = 0.f;
#pragma unroll
    for (int lq = 0; lq < 4; ++lq) {
      a0 += rws4[(((size_t)b * 4 + h) * 4 + lq) * 128 + t];
      a1 += rws4[(((size_t)(64 + b) * 4 + h) * 4 + lq) * 128 + t];
    }
    r1h[h] = a0;
    r2h[h] = a1;
    r2l[h][t] = a1;
  }
  __syncthreads();
  float p[4] = {0, 0, 0, 0};
  for (int e = 0; e < 128; ++e) {
    float w = Wipm[t * 128 + e];
#pragma unroll
    for (int h = 0; h < 4; ++h) p[h] += w * r2l[h][e];
  }
#pragma unroll
  for (int h = 0; h < 4; ++h) p[h] *= r1h[h];
#pragma unroll
  for (int off = 1; off < 64; off <<= 1)
#pragma unroll
    for (int h = 0; h < 4; ++h) p[h] += __shfl_xor(p[h], off);
  if ((t & 63) == 0)
#pragma unroll
    for (int h = 0; h < 4; ++h) tsum[t >> 6][h] = p[h];
  __syncthreads();
  float ad[4], mx = -3.0e38f;
#pragma unroll
  for (int h = 0; h < 4; ++h) {
    float v = tanhf(tsum[0][h] + tsum[1][h]);
    ad[h] = v;
    mx = fmaxf(mx, v);
  }
  float s = 0.0f;
#pragma unroll
  for (int h = 0; h < 4; ++h) { ad[h] = expf(ad[h] - mx); s += ad[h]; }
  float inv = 1.0f / s;
#pragma unroll
  for (int h = 0; h < 4; ++h) ad[h] *= inv;
  if (t < 4) out[278528 + b * 4 + t] = ad[t];
  float f1 = 0.0f, f2 = 0.0f;
#pragma unroll
  for (int h = 0; h < 4; ++h) { f1 += ad[h] * r1h[h]; f2 += ad[h] * r2h[h]; }
  out[b * 128 + t] = f1;
  out[8192 + b * 128 + t] = f2;
}

extern "C" void kernel_launch(void* const* d_in, const int* in_sizes, int n_in,
                              void* d_out, int out_size, void* d_ws,
                              size_t ws_size, hipStream_t stream) {
  (void)in_sizes; (void)n_in; (void)out_size; (void)ws_size;
  const float* x1 = (const float*)d_in[0];
  const float* x2 = (const float*)d_in[1];
  const int* raw1 = (const int*)d_in[2];
  const int* raw2 = (const int*)d_in[3];
  const float* wu = (const float*)d_in[4];
  const float* wipm = (const float*)d_in[5];
  float* out = (float*)d_out;
  char* w = (char*)d_ws;
  unsigned short* x2h = (unsigned short*)(w);             // 8 MiB
  unsigned short* x2l = (unsigned short*)(w + 8388608);   // 8 MiB
  unsigned short* wimg = (unsigned short*)(w + 16777216); // 256 KiB
  float* s1pp = (float*)(w + 17039360);                   // 1 MiB [bh][mhalf][512]
  float* s2 = (float*)(w + 18087936);                     // 512 KiB [bh][512]
  float* rws4 = (float*)(w + 18612224);                   // 1 MiB

  kx<<<2048, 256, 0, stream>>>(x2, x2h, x2l);
  kw<<<32, 256, 0, stream>>>(wu, wimg);
  k1<<<512, 512, 0, stream>>>(x1, x2h, x2l, wimg, raw1, raw2, s1pp, s2);
  k2<<<512, 256, 0, stream>>>(s1pp, s2, x1, x2, out, rws4);
  k3<<<64, 128, 0, stream>>>(rws4, wipm, out);
}

// Round 7
// 114.242 us; speedup vs baseline: 1.5905x; 1.5905x over previous
//
#include <hip/hip_runtime.h>

#define Bn 64
#define Dn 128
#define Ln 512

typedef __attribute__((ext_vector_type(8))) short short8;
typedef __attribute__((ext_vector_type(4))) float f32x4;

// truncating bf16 split: x ~= hi + lo
__device__ __forceinline__ void split8(const float* xs, short8& hi, short8& lo) {
#pragma unroll
  for (int j = 0; j < 8; ++j) {
    unsigned int u = __float_as_uint(xs[j]);
    float l = xs[j] - __uint_as_float(u & 0xFFFF0000u);
    hi[j] = (short)(u >> 16);
    lo[j] = (short)(__float_as_uint(l) >> 16);
  }
}

// ---- kw: pre-split W_U -> frag-ordered images ----
// unit (h,dgrp,ks,comp) 512 ushorts; lane ln: d=dgrp*16+(ln&15), e=ks*32+(ln>>4)*8
__global__ __launch_bounds__(256) void kw(const float* __restrict__ WU,
                                          unsigned short* __restrict__ wimg) {
  int blk = blockIdx.x;  // 32: h = blk>>3, dgrp = blk&7
  int t = threadIdx.x, ln = t & 63, ks = t >> 6;
  int h = blk >> 3, dgrp = blk & 7;
  int d = dgrp * 16 + (ln & 15), e = ks * 32 + (ln >> 4) * 8;
  const float* src = WU + ((size_t)h * Dn + d) * Dn + e;
  float xs[8];
  *(float4*)xs = *(const float4*)src;
  *(float4*)(xs + 4) = *(const float4*)(src + 4);
  short8 hi, lo;
  split8(xs, hi, lo);
  size_t u = (size_t)(((h * 8 + dgrp) * 4 + ks) * 2) * 512 + (size_t)ln * 8;
  *(short8*)(wimg + u) = hi;
  *(short8*)(wimg + u + 512) = lo;
}

// ---- kz: Z[bh][m][d] = sum_e X2[m,b,e] WU[h,d,e]. k1-shaped codegen:
// A = X2 rows resident in regs; B = WU frags streamed from wimg (L2-hot).
// grid 1024: blk = b*16 + mt*4 + h. Writes R4-layout zimg via LDS transpose.
__global__ __launch_bounds__(256, 2) void kz(const float* __restrict__ X2,
                                             const unsigned short* __restrict__ wimg,
                                             unsigned short* __restrict__ zimg) {
  __shared__ __align__(16) float zt[128 * 132];
  int orig = blockIdx.x;
  int blk = (orig & 7) * 128 + (orig >> 3);  // XCD swizzle
  int h = blk & 3, mt = (blk >> 2) & 3, b = blk >> 4;
  int t = threadIdx.x, ln = t & 63, wv = t >> 6;
  int rg = wv >> 1, cb = wv & 1;
  int R0 = rg * 64;

  // A resident: X2 rows mt*128 + R0 + mr*16 + (ln&15), k = ks*32 + (ln>>4)*8
  short8 ahf[4][4], alf[4][4];
  {
    int eo = (ln >> 4) * 8;
#pragma unroll
    for (int mr = 0; mr < 4; ++mr) {
      const float* rsrc =
          X2 + ((size_t)(mt * 128 + R0 + mr * 16 + (ln & 15)) * Bn + b) * Dn + eo;
#pragma unroll
      for (int ks = 0; ks < 4; ++ks) {
        float xs[8];
        *(float4*)xs = *(const float4*)(rsrc + ks * 32);
        *(float4*)(xs + 4) = *(const float4*)(rsrc + ks * 32 + 4);
        split8(xs, ahf[mr][ks], alf[mr][ks]);
      }
    }
  }

  const f32x4 fz = {0.f, 0.f, 0.f, 0.f};
#pragma unroll
  for (int ph = 0; ph < 2; ++ph) {  // d cols = cb*64 + ph*32
    f32x4 acc[4][2];
#pragma unroll
    for (int i = 0; i < 4; ++i) {
      acc[i][0] = fz;
      acc[i][1] = fz;
    }
    int dg0 = cb * 4 + ph * 2;
#pragma unroll
    for (int ks = 0; ks < 4; ++ks) {
      const unsigned short* ub =
          wimg + ((size_t)(((h * 8 + dg0) * 4 + ks) * 2)) * 512 + (size_t)ln * 8;
      short8 b0h = *(const short8*)ub;
      short8 b0l = *(const short8*)(ub + 512);
      short8 b1h = *(const short8*)(ub + 4096);
      short8 b1l = *(const short8*)(ub + 4608);
#pragma unroll
      for (int mr = 0; mr < 4; ++mr) {
        acc[mr][0] = __builtin_amdgcn_mfma_f32_16x16x32_bf16(ahf[mr][ks], b0h, acc[mr][0], 0, 0, 0);
        acc[mr][0] = __builtin_amdgcn_mfma_f32_16x16x32_bf16(ahf[mr][ks], b0l, acc[mr][0], 0, 0, 0);
        acc[mr][0] = __builtin_amdgcn_mfma_f32_16x16x32_bf16(alf[mr][ks], b0h, acc[mr][0], 0, 0, 0);
        acc[mr][1] = __builtin_amdgcn_mfma_f32_16x16x32_bf16(ahf[mr][ks], b1h, acc[mr][1], 0, 0, 0);
        acc[mr][1] = __builtin_amdgcn_mfma_f32_16x16x32_bf16(ahf[mr][ks], b1l, acc[mr][1], 0, 0, 0);
        acc[mr][1] = __builtin_amdgcn_mfma_f32_16x16x32_bf16(alf[mr][ks], b1h, acc[mr][1], 0, 0, 0);
      }
    }
    // acc -> zt rows m, cols d. C layout: col=ln&15, row=(ln>>4)*4+j
#pragma unroll
    for (int mr = 0; mr < 4; ++mr) {
      int rb = R0 + mr * 16 + (ln >> 4) * 4;
#pragma unroll
      for (int nr = 0; nr < 2; ++nr) {
        int d = cb * 64 + ph * 32 + nr * 16 + (ln & 15);
#pragma unroll
        for (int j = 0; j < 4; ++j) zt[(rb + j) * 132 + d] = acc[mr][nr][j];
      }
    }
  }
  __syncthreads();
  // R4-verified epilogue: zt -> frag-ordered zimg units for (bh, mt)
  int bh = b * 4 + h;
#pragma unroll
  for (int p = 0; p < 8; ++p) {
    int u = p * 4 + (t >> 6);  // 0..31 : (mgrp_local = u>>2, ks = u&3)
    int r = (u >> 2) * 16 + (ln & 15);
    int d = (u & 3) * 32 + (ln >> 4) * 8;
    float xs[8];
    *(float4*)xs = *(const float4*)(zt + r * 132 + d);
    *(float4*)(xs + 4) = *(const float4*)(zt + r * 132 + d + 4);
    short8 hi, lo;
    split8(xs, hi, lo);
    size_t ub = ((((size_t)bh * 32 + mt * 8 + (u >> 2)) * 4 + (u & 3)) * 2) * 512 + (size_t)ln * 8;
    *(short8*)(zimg + ub) = hi;
    *(short8*)(zimg + ub + 512) = lo;
  }
}

// ---- k1: masked row/col maxes of S = X1 . Z^T. grid 1024: b*16+h*4+lt.
// (R4 verbatim) Barrier-free main loop; A resident, B streamed global->regs.
__global__ __launch_bounds__(256, 2) void k1(const float* __restrict__ X1,
                                             const unsigned short* __restrict__ zimg,
                                             const int* __restrict__ raw1,
                                             const int* __restrict__ raw2,
                                             float* __restrict__ s1pp,
                                             float* __restrict__ s2pp) {
  __shared__ float m1f[128];
  __shared__ float m2f[512];
  __shared__ float cmbuf[2][512];  // [rg][col] colmax partials

  int orig = blockIdx.x;
  int blk = (orig & 7) * 128 + (orig >> 3);
  int lt = blk & 3, h = (blk >> 2) & 3, b = blk >> 4;
  int bh = b * 4 + h;
  int t = threadIdx.x, ln = t & 63, wv = t >> 6;
  int rg = wv >> 1, cb = wv & 1;
  int R0 = rg * 64;

  for (int i = t; i < 512; i += 256) m2f[i] = (raw2[(size_t)i * Bn + b] == 0) ? 1.0e4f : 0.0f;
  if (t < 128) m1f[t] = (raw1[(size_t)(lt * 128 + t) * Bn + b] == 0) ? 1.0e4f : 0.0f;

  // A resident: rows lt*128 + R0 + mr*16 + (ln&15), k = ks*32 + (ln>>4)*8
  short8 ahf[4][4], alf[4][4];
  {
    int eo = (ln >> 4) * 8;
#pragma unroll
    for (int mr = 0; mr < 4; ++mr) {
      const float* rsrc =
          X1 + ((size_t)(lt * 128 + R0 + mr * 16 + (ln & 15)) * Bn + b) * Dn + eo;
#pragma unroll
      for (int ks = 0; ks < 4; ++ks) {
        float xs[8];
        *(float4*)xs = *(const float4*)(rsrc + ks * 32);
        *(float4*)(xs + 4) = *(const float4*)(rsrc + ks * 32 + 4);
        split8(xs, ahf[mr][ks], alf[mr][ks]);
      }
    }
  }
  __syncthreads();  // masks ready

  float msub1[4][4];
#pragma unroll
  for (int mr = 0; mr < 4; ++mr)
#pragma unroll
    for (int j = 0; j < 4; ++j) msub1[mr][j] = m1f[R0 + mr * 16 + (ln >> 4) * 4 + j];

  float rmrun[4][4];
#pragma unroll
  for (int i = 0; i < 4; ++i)
#pragma unroll
    for (int j = 0; j < 4; ++j) rmrun[i][j] = -3.0e38f;

  const f32x4 fz = {0.f, 0.f, 0.f, 0.f};
  for (int ph = 0; ph < 8; ++ph) {  // cols = cb*256 + ph*32
    int cg = cb * 16 + ph * 2;
    f32x4 acc[4][2];
#pragma unroll
    for (int i = 0; i < 4; ++i) {
      acc[i][0] = fz;
      acc[i][1] = fz;
    }
#pragma unroll
    for (int ks = 0; ks < 4; ++ks) {
      const unsigned short* ubase =
          zimg + ((((size_t)bh * 32 + cg) * 4 + ks) * 2) * 512 + (size_t)ln * 8;
      short8 b0h = *(const short8*)ubase;
      short8 b0l = *(const short8*)(ubase + 512);
      short8 b1h = *(const short8*)(ubase + 4096);
      short8 b1l = *(const short8*)(ubase + 4608);
#pragma unroll
      for (int mr = 0; mr < 4; ++mr) {
        acc[mr][0] = __builtin_amdgcn_mfma_f32_16x16x32_bf16(ahf[mr][ks], b0h, acc[mr][0], 0, 0, 0);
        acc[mr][0] = __builtin_amdgcn_mfma_f32_16x16x32_bf16(ahf[mr][ks], b0l, acc[mr][0], 0, 0, 0);
        acc[mr][0] = __builtin_amdgcn_mfma_f32_16x16x32_bf16(alf[mr][ks], b0h, acc[mr][0], 0, 0, 0);
        acc[mr][1] = __builtin_amdgcn_mfma_f32_16x16x32_bf16(ahf[mr][ks], b1h, acc[mr][1], 0, 0, 0);
        acc[mr][1] = __builtin_amdgcn_mfma_f32_16x16x32_bf16(ahf[mr][ks], b1l, acc[mr][1], 0, 0, 0);
        acc[mr][1] = __builtin_amdgcn_mfma_f32_16x16x32_bf16(alf[mr][ks], b1h, acc[mr][1], 0, 0, 0);
      }
    }
    // masked reductions
    float ms0 = m2f[cb * 256 + ph * 32 + (ln & 15)];
    float ms1 = m2f[cb * 256 + ph * 32 + 16 + (ln & 15)];
#pragma unroll
    for (int mr = 0; mr < 4; ++mr)
#pragma unroll
      for (int j = 0; j < 4; ++j) {
        float c = fmaxf(acc[mr][0][j] - ms0, acc[mr][1][j] - ms1);
        rmrun[mr][j] = fmaxf(rmrun[mr][j], c);
      }
#pragma unroll
    for (int nr = 0; nr < 2; ++nr) {
      float v = -3.0e38f;
#pragma unroll
      for (int mr = 0; mr < 4; ++mr)
#pragma unroll
        for (int j = 0; j < 4; ++j) v = fmaxf(v, acc[mr][nr][j] - msub1[mr][j]);
      v = fmaxf(v, __shfl_xor(v, 16));
      v = fmaxf(v, __shfl_xor(v, 32));
      if (ln < 16) cmbuf[rg][cb * 256 + ph * 32 + nr * 16 + ln] = v;
    }
  }

  // epilogue: rowmax cross-lane + writes
#pragma unroll
  for (int off = 1; off < 16; off <<= 1)
#pragma unroll
    for (int mr = 0; mr < 4; ++mr)
#pragma unroll
      for (int j = 0; j < 4; ++j)
        rmrun[mr][j] = fmaxf(rmrun[mr][j], __shfl_xor(rmrun[mr][j], off));
  if ((ln & 15) == 0) {
    float* dst = s1pp + (((size_t)bh * 4 + lt) * 2 + cb) * 128;
#pragma unroll
    for (int mr = 0; mr < 4; ++mr)
#pragma unroll
      for (int j = 0; j < 4; ++j) dst[R0 + mr * 16 + (ln >> 4) * 4 + j] = rmrun[mr][j];
  }
  __syncthreads();
  for (int i = t; i < 1024; i += 256) {
    int rgi = i >> 9, col = i & 511;
    s2pp[(((size_t)bh * 4 + lt) * 2 + rgi) * 512 + col] = cmbuf[rgi][col];
  }
}

// ---- k2: (side,b,lq): wave h = tanh+softmax; partial readout over l-quarter
__global__ __launch_bounds__(256) void k2(const float* __restrict__ s1pp,
                                          const float* __restrict__ s2pp,
                                          const float* __restrict__ X1,
                                          const float* __restrict__ X2,
                                          float* __restrict__ out,
                                          float* __restrict__ rws4) {
  __shared__ float aL[4][512];
  __shared__ f32x4 redv[4][8][32];
  int blk = blockIdx.x;  // 512
  int side = blk >> 8, b = (blk >> 2) & 63, lq = blk & 3;
  int t = threadIdx.x, ln = t & 63, h = t >> 6;
  int bh = b * 4 + h;
  int base = ln * 8;

  float vals[8];
  if (side == 0) {
    int lt = base >> 7, r = base & 127;
    const float* p0 = s1pp + (((size_t)bh * 4 + lt) * 2) * 128 + r;
#pragma unroll
    for (int q = 0; q < 8; q += 4) {
      float4 va = *(const float4*)(p0 + q);
      float4 vb = *(const float4*)(p0 + 128 + q);
      vals[q + 0] = fmaxf(va.x, vb.x);
      vals[q + 1] = fmaxf(va.y, vb.y);
      vals[q + 2] = fmaxf(va.z, vb.z);
      vals[q + 3] = fmaxf(va.w, vb.w);
    }
  } else {
#pragma unroll
    for (int q = 0; q < 8; ++q) vals[q] = -3.0e38f;
#pragma unroll
    for (int sl = 0; sl < 8; ++sl) {
      const float* p = s2pp + (((size_t)bh * 4 + (sl >> 1)) * 2 + (sl & 1)) * 512 + base;
#pragma unroll
      for (int q = 0; q < 8; q += 4) {
        float4 v = *(const float4*)(p + q);
        vals[q + 0] = fmaxf(vals[q + 0], v.x);
        vals[q + 1] = fmaxf(vals[q + 1], v.y);
        vals[q + 2] = fmaxf(vals[q + 2], v.z);
        vals[q + 3] = fmaxf(vals[q + 3], v.w);
      }
    }
  }
#pragma unroll
  for (int q = 0; q < 8; ++q) vals[q] = tanhf(vals[q]);
  float mx = vals[0];
#pragma unroll
  for (int q = 1; q < 8; ++q) mx = fmaxf(mx, vals[q]);
#pragma unroll
  for (int off = 1; off < 64; off <<= 1) mx = fmaxf(mx, __shfl_xor(mx, off));
  float s = 0.0f;
#pragma unroll
  for (int q = 0; q < 8; ++q) {
    vals[q] = expf(vals[q] - mx);
    s += vals[q];
  }
#pragma unroll
  for (int off = 1; off < 64; off <<= 1) s += __shfl_xor(s, off);
  float inv = 1.0f / s;
#pragma unroll
  for (int q = 0; q < 8; ++q) vals[q] *= inv;

  if (lq == 0) {
    int aoff = (side == 0 ? 16384 : 147456) + bh * 512 + base;
    *(float4*)(out + aoff) = make_float4(vals[0], vals[1], vals[2], vals[3]);
    *(float4*)(out + aoff + 4) = make_float4(vals[4], vals[5], vals[6], vals[7]);
  }
  *(float4*)(&aL[h][base]) = make_float4(vals[0], vals[1], vals[2], vals[3]);
  *(float4*)(&aL[h][base + 4]) = make_float4(vals[4], vals[5], vals[6], vals[7]);
  __syncthreads();

  // partial readout over l in [lq*128, +128)
  const float4* X4 = (const float4*)(side == 0 ? X1 : X2);
  int q = t & 31, lg = t >> 5;
  f32x4 av[4];
  const f32x4 fz = {0.f, 0.f, 0.f, 0.f};
#pragma unroll
  for (int hh = 0; hh < 4; ++hh) av[hh] = fz;
#pragma unroll 4
  for (int l = lq * 128 + lg; l < lq * 128 + 128; l += 8) {
    float4 xv = X4[((size_t)l * Bn + b) * 32 + q];
#pragma unroll
    for (int hh = 0; hh < 4; ++hh) {
      float w = aL[hh][l];
      av[hh][0] += w * xv.x;
      av[hh][1] += w * xv.y;
      av[hh][2] += w * xv.z;
      av[hh][3] += w * xv.w;
    }
  }
#pragma unroll
  for (int hh = 0; hh < 4; ++hh) redv[hh][lg][q] = av[hh];
  __syncthreads();
  if (t < 128) {
    int d = t;
#pragma unroll
    for (int hh = 0; hh < 4; ++hh) {
      float s2v = 0.0f;
#pragma unroll
      for (int g = 0; g < 8; ++g) s2v += ((const float*)&redv[hh][g][d >> 2])[d & 3];
      rws4[(((size_t)(side * 64 + b) * 4 + hh) * 4 + lq) * 128 + d] = s2v;
    }
  }
}

// ---- k3: combine hops (sums lq partials) ----
__global__ __launch_bounds__(128) void k3(const float* __restrict__ rws4,
                                          const float* __restrict__ Wipm,
                                          float* __restrict__ out) {
  int b = blockIdx.x, t = threadIdx.x;  // t = d
  __shared__ float r2l[4][128];
  __shared__ float tsum[2][4];
  float r1h[4], r2h[4];
#pragma unroll
  for (int h = 0; h < 4; ++h) {
    float a0 = 0.f, a1 = 0.f;
#pragma unroll
    for (int lq = 0; lq < 4; ++lq) {
      a0 += rws4[(((size_t)b * 4 + h) * 4 + lq) * 128 + t];
      a1 += rws4[(((size_t)(64 + b) * 4 + h) * 4 + lq) * 128 + t];
    }
    r1h[h] = a0;
    r2h[h] = a1;
    r2l[h][t] = a1;
  }
  __syncthreads();
  float p[4] = {0, 0, 0, 0};
  for (int e = 0; e < 128; ++e) {
    float w = Wipm[t * 128 + e];
#pragma unroll
    for (int h = 0; h < 4; ++h) p[h] += w * r2l[h][e];
  }
#pragma unroll
  for (int h = 0; h < 4; ++h) p[h] *= r1h[h];
#pragma unroll
  for (int off = 1; off < 64; off <<= 1)
#pragma unroll
    for (int h = 0; h < 4; ++h) p[h] += __shfl_xor(p[h], off);
  if ((t & 63) == 0)
#pragma unroll
    for (int h = 0; h < 4; ++h) tsum[t >> 6][h] = p[h];
  __syncthreads();
  float ad[4], mx = -3.0e38f;
#pragma unroll
  for (int h = 0; h < 4; ++h) {
    float v = tanhf(tsum[0][h] + tsum[1][h]);
    ad[h] = v;
    mx = fmaxf(mx, v);
  }
  float s = 0.0f;
#pragma unroll
  for (int h = 0; h < 4; ++h) { ad[h] = expf(ad[h] - mx); s += ad[h]; }
  float inv = 1.0f / s;
#pragma unroll
  for (int h = 0; h < 4; ++h) ad[h] *= inv;
  if (t < 4) out[278528 + b * 4 + t] = ad[t];
  float f1 = 0.0f, f2 = 0.0f;
#pragma unroll
  for (int h = 0; h < 4; ++h) { f1 += ad[h] * r1h[h]; f2 += ad[h] * r2h[h]; }
  out[b * 128 + t] = f1;
  out[8192 + b * 128 + t] = f2;
}

extern "C" void kernel_launch(void* const* d_in, const int* in_sizes, int n_in,
                              void* d_out, int out_size, void* d_ws,
                              size_t ws_size, hipStream_t stream) {
  (void)in_sizes; (void)n_in; (void)out_size; (void)ws_size;
  const float* x1 = (const float*)d_in[0];
  const float* x2 = (const float*)d_in[1];
  const int* raw1 = (const int*)d_in[2];
  const int* raw2 = (const int*)d_in[3];
  const float* wu = (const float*)d_in[4];
  const float* wipm = (const float*)d_in[5];
  float* out = (float*)d_out;
  char* w = (char*)d_ws;
  unsigned short* zimg = (unsigned short*)w;            // 64 MiB
  unsigned short* wimg = (unsigned short*)(w + 67108864);  // 512 KiB
  float* s1pp = (float*)(w + 67633152);                 // 1 MiB  [bh][lt][cb][128]
  float* s2pp = (float*)(w + 68681728);                 // 4 MiB  [bh][lt][rg][512]
  float* rws4 = (float*)(w + 72876032);                 // 1 MiB

  kw<<<32, 256, 0, stream>>>(wu, wimg);
  kz<<<1024, 256, 0, stream>>>(x2, wimg, zimg);
  k1<<<1024, 256, 0, stream>>>(x1, zimg, raw1, raw2, s1pp, s2pp);
  k2<<<512, 256, 0, stream>>>(s1pp, s2pp, x1, x2, out, rws4);
  k3<<<64, 128, 0, stream>>>(rws4, wipm, out);
}

// Round 8
// 103.152 us; speedup vs baseline: 1.7615x; 1.1075x over previous
//
#include <hip/hip_runtime.h>

#define Bn 64
#define Dn 128
#define Ln 512

typedef __attribute__((ext_vector_type(8))) short short8;
typedef __attribute__((ext_vector_type(4))) float f32x4;

// truncating bf16 split: x ~= hi + lo
__device__ __forceinline__ void split8(const float* xs, short8& hi, short8& lo) {
#pragma unroll
  for (int j = 0; j < 8; ++j) {
    unsigned int u = __float_as_uint(xs[j]);
    float l = xs[j] - __uint_as_float(u & 0xFFFF0000u);
    hi[j] = (short)(u >> 16);
    lo[j] = (short)(__float_as_uint(l) >> 16);
  }
}
__device__ __forceinline__ void gll16(const void* g, void* l) {
  __builtin_amdgcn_global_load_lds(
      (const __attribute__((address_space(1))) void*)g,
      (__attribute__((address_space(3))) void*)l, 16, 0, 0);
}

// ---- kw: pre-split W_U -> frag-ordered images ----
__global__ __launch_bounds__(256) void kw(const float* __restrict__ WU,
                                          unsigned short* __restrict__ wimg) {
  int blk = blockIdx.x;  // 32: h = blk>>3, dgrp = blk&7
  int t = threadIdx.x, ln = t & 63, ks = t >> 6;
  int h = blk >> 3, dgrp = blk & 7;
  int d = dgrp * 16 + (ln & 15), e = ks * 32 + (ln >> 4) * 8;
  const float* src = WU + ((size_t)h * Dn + d) * Dn + e;
  float xs[8];
  *(float4*)xs = *(const float4*)src;
  *(float4*)(xs + 4) = *(const float4*)(src + 4);
  short8 hi, lo;
  split8(xs, hi, lo);
  size_t u = (size_t)(((h * 8 + dgrp) * 4 + ks) * 2) * 512 + (size_t)ln * 8;
  *(short8*)(wimg + u) = hi;
  *(short8*)(wimg + u + 512) = lo;
}

// ---- kz: Z[bh][m][d] = sum_e X2[m,b,e] WU[h,d,e] (R7 verbatim) ----
__global__ __launch_bounds__(256, 2) void kz(const float* __restrict__ X2,
                                             const unsigned short* __restrict__ wimg,
                                             unsigned short* __restrict__ zimg) {
  __shared__ __align__(16) float zt[128 * 132];
  int orig = blockIdx.x;
  int blk = (orig & 7) * 128 + (orig >> 3);  // XCD swizzle
  int h = blk & 3, mt = (blk >> 2) & 3, b = blk >> 4;
  int t = threadIdx.x, ln = t & 63, wv = t >> 6;
  int rg = wv >> 1, cb = wv & 1;
  int R0 = rg * 64;

  short8 ahf[4][4], alf[4][4];
  {
    int eo = (ln >> 4) * 8;
#pragma unroll
    for (int mr = 0; mr < 4; ++mr) {
      const float* rsrc =
          X2 + ((size_t)(mt * 128 + R0 + mr * 16 + (ln & 15)) * Bn + b) * Dn + eo;
#pragma unroll
      for (int ks = 0; ks < 4; ++ks) {
        float xs[8];
        *(float4*)xs = *(const float4*)(rsrc + ks * 32);
        *(float4*)(xs + 4) = *(const float4*)(rsrc + ks * 32 + 4);
        split8(xs, ahf[mr][ks], alf[mr][ks]);
      }
    }
  }

  const f32x4 fz = {0.f, 0.f, 0.f, 0.f};
#pragma unroll
  for (int ph = 0; ph < 2; ++ph) {  // d cols = cb*64 + ph*32
    f32x4 acc[4][2];
#pragma unroll
    for (int i = 0; i < 4; ++i) {
      acc[i][0] = fz;
      acc[i][1] = fz;
    }
    int dg0 = cb * 4 + ph * 2;
#pragma unroll
    for (int ks = 0; ks < 4; ++ks) {
      const unsigned short* ub =
          wimg + ((size_t)(((h * 8 + dg0) * 4 + ks) * 2)) * 512 + (size_t)ln * 8;
      short8 b0h = *(const short8*)ub;
      short8 b0l = *(const short8*)(ub + 512);
      short8 b1h = *(const short8*)(ub + 4096);
      short8 b1l = *(const short8*)(ub + 4608);
#pragma unroll
      for (int mr = 0; mr < 4; ++mr) {
        acc[mr][0] = __builtin_amdgcn_mfma_f32_16x16x32_bf16(ahf[mr][ks], b0h, acc[mr][0], 0, 0, 0);
        acc[mr][0] = __builtin_amdgcn_mfma_f32_16x16x32_bf16(ahf[mr][ks], b0l, acc[mr][0], 0, 0, 0);
        acc[mr][0] = __builtin_amdgcn_mfma_f32_16x16x32_bf16(alf[mr][ks], b0h, acc[mr][0], 0, 0, 0);
        acc[mr][1] = __builtin_amdgcn_mfma_f32_16x16x32_bf16(ahf[mr][ks], b1h, acc[mr][1], 0, 0, 0);
        acc[mr][1] = __builtin_amdgcn_mfma_f32_16x16x32_bf16(ahf[mr][ks], b1l, acc[mr][1], 0, 0, 0);
        acc[mr][1] = __builtin_amdgcn_mfma_f32_16x16x32_bf16(alf[mr][ks], b1h, acc[mr][1], 0, 0, 0);
      }
    }
#pragma unroll
    for (int mr = 0; mr < 4; ++mr) {
      int rb = R0 + mr * 16 + (ln >> 4) * 4;
#pragma unroll
      for (int nr = 0; nr < 2; ++nr) {
        int d = cb * 64 + ph * 32 + nr * 16 + (ln & 15);
#pragma unroll
        for (int j = 0; j < 4; ++j) zt[(rb + j) * 132 + d] = acc[mr][nr][j];
      }
    }
  }
  __syncthreads();
  int bh = b * 4 + h;
#pragma unroll
  for (int p = 0; p < 8; ++p) {
    int u = p * 4 + (t >> 6);
    int r = (u >> 2) * 16 + (ln & 15);
    int d = (u & 3) * 32 + (ln >> 4) * 8;
    float xs[8];
    *(float4*)xs = *(const float4*)(zt + r * 132 + d);
    *(float4*)(xs + 4) = *(const float4*)(zt + r * 132 + d + 4);
    short8 hi, lo;
    split8(xs, hi, lo);
    size_t ub = ((((size_t)bh * 32 + mt * 8 + (u >> 2)) * 4 + (u & 3)) * 2) * 512 + (size_t)ln * 8;
    *(short8*)(zimg + ub) = hi;
    *(short8*)(zimg + ub + 512) = lo;
  }
}

// ---- k1 mega-block: per (b,h), all 512 rows resident (8 waves x 64 rows).
// B chunks (32 cols, 16KB contiguous) staged once via global_load_lds,
// double-buffered, broadcast-read by all waves. grid 256 x 512 thr. ----
__global__ __launch_bounds__(512, 2) void k1(const float* __restrict__ X1,
                                             const unsigned short* __restrict__ zimg,
                                             const int* __restrict__ raw1,
                                             const int* __restrict__ raw2,
                                             float* __restrict__ s1,
                                             float* __restrict__ s2) {
  __shared__ __align__(16) char Bbuf[2][16384];
  __shared__ float m1f[512];
  __shared__ float m2f[512];
  __shared__ float cmbuf[8][512];

  int orig = blockIdx.x;
  int blk = (orig & 7) * 32 + (orig >> 3);  // XCD swizzle (256 = 8*32)
  int h = blk & 3, b = blk >> 2;
  int bh = b * 4 + h;
  int t = threadIdx.x, ln = t & 63, wv = t >> 6;
  int R0 = wv * 64;

  m1f[t] = (raw1[(size_t)t * Bn + b] == 0) ? 1.0e4f : 0.0f;
  m2f[t] = (raw2[(size_t)t * Bn + b] == 0) ? 1.0e4f : 0.0f;

  // chunk c = cg pair {2c, 2c+1}: 16 KB contiguous at ushort (bh*32 + 2c)*4096
#define STAGE(bb, c_)                                                       \
  {                                                                         \
    size_t ub = ((size_t)bh * 32 + (c_)*2) * 4096 + wv * 1024;              \
    gll16(zimg + ub + (size_t)ln * 8, Bbuf[bb] + wv * 2048);                \
    gll16(zimg + ub + 512 + (size_t)ln * 8, Bbuf[bb] + wv * 2048 + 1024);   \
  }

  STAGE(0, 0);

  // A resident: rows R0 + mr*16 + (ln&15), k = ks*32 + (ln>>4)*8
  short8 ahf[4][4], alf[4][4];
  {
    int eo = (ln >> 4) * 8;
#pragma unroll
    for (int mr = 0; mr < 4; ++mr) {
      const float* rsrc =
          X1 + ((size_t)(R0 + mr * 16 + (ln & 15)) * Bn + b) * Dn + eo;
#pragma unroll
      for (int ks = 0; ks < 4; ++ks) {
        float xs[8];
        *(float4*)xs = *(const float4*)(rsrc + ks * 32);
        *(float4*)(xs + 4) = *(const float4*)(rsrc + ks * 32 + 4);
        split8(xs, ahf[mr][ks], alf[mr][ks]);
      }
    }
  }
  __syncthreads();  // stage(0) landed + masks ready

  float msub1[4][4];
#pragma unroll
  for (int mr = 0; mr < 4; ++mr)
#pragma unroll
    for (int j = 0; j < 4; ++j) msub1[mr][j] = m1f[R0 + mr * 16 + (ln >> 4) * 4 + j];

  float rmrun[4][4];
#pragma unroll
  for (int i = 0; i < 4; ++i)
#pragma unroll
    for (int j = 0; j < 4; ++j) rmrun[i][j] = -3.0e38f;

  const f32x4 fz = {0.f, 0.f, 0.f, 0.f};
  int cur = 0;
  for (int c = 0; c < 16; ++c) {  // cols = c*32 .. +32
    if (c < 15) STAGE(cur ^ 1, c + 1);  // issue-early; ages under compute

    f32x4 acc[4][2];
#pragma unroll
    for (int i = 0; i < 4; ++i) {
      acc[i][0] = fz;
      acc[i][1] = fz;
    }
#pragma unroll
    for (int ks = 0; ks < 4; ++ks) {
      // chunk layout: [cg2][ks][comp][1KB]; lane ln at +ln*16
      const char* base = Bbuf[cur] + ks * 2048 + ln * 16;
      short8 b0h = *(const short8*)base;
      short8 b0l = *(const short8*)(base + 1024);
      short8 b1h = *(const short8*)(base + 8192);
      short8 b1l = *(const short8*)(base + 9216);
#pragma unroll
      for (int mr = 0; mr < 4; ++mr) {
        acc[mr][0] = __builtin_amdgcn_mfma_f32_16x16x32_bf16(ahf[mr][ks], b0h, acc[mr][0], 0, 0, 0);
        acc[mr][0] = __builtin_amdgcn_mfma_f32_16x16x32_bf16(ahf[mr][ks], b0l, acc[mr][0], 0, 0, 0);
        acc[mr][0] = __builtin_amdgcn_mfma_f32_16x16x32_bf16(alf[mr][ks], b0h, acc[mr][0], 0, 0, 0);
        acc[mr][1] = __builtin_amdgcn_mfma_f32_16x16x32_bf16(ahf[mr][ks], b1h, acc[mr][1], 0, 0, 0);
        acc[mr][1] = __builtin_amdgcn_mfma_f32_16x16x32_bf16(ahf[mr][ks], b1l, acc[mr][1], 0, 0, 0);
        acc[mr][1] = __builtin_amdgcn_mfma_f32_16x16x32_bf16(alf[mr][ks], b1h, acc[mr][1], 0, 0, 0);
      }
    }
    // masked reductions (R4 pattern)
    float ms0 = m2f[c * 32 + (ln & 15)];
    float ms1 = m2f[c * 32 + 16 + (ln & 15)];
#pragma unroll
    for (int mr = 0; mr < 4; ++mr)
#pragma unroll
      for (int j = 0; j < 4; ++j) {
        float cc = fmaxf(acc[mr][0][j] - ms0, acc[mr][1][j] - ms1);
        rmrun[mr][j] = fmaxf(rmrun[mr][j], cc);
      }
#pragma unroll
    for (int nr = 0; nr < 2; ++nr) {
      float v = -3.0e38f;
#pragma unroll
      for (int mr = 0; mr < 4; ++mr)
#pragma unroll
        for (int j = 0; j < 4; ++j) v = fmaxf(v, acc[mr][nr][j] - msub1[mr][j]);
      v = fmaxf(v, __shfl_xor(v, 16));
      v = fmaxf(v, __shfl_xor(v, 32));
      if (ln < 16) cmbuf[wv][c * 32 + nr * 16 + ln] = v;
    }
    __syncthreads();  // buf[cur] reads done; stage(cur^1) landed
    cur ^= 1;
  }
#undef STAGE

  // rowmax cross-lane + write (complete: all 512 cols seen)
#pragma unroll
  for (int off = 1; off < 16; off <<= 1)
#pragma unroll
    for (int mr = 0; mr < 4; ++mr)
#pragma unroll
      for (int j = 0; j < 4; ++j)
        rmrun[mr][j] = fmaxf(rmrun[mr][j], __shfl_xor(rmrun[mr][j], off));
  if ((ln & 15) == 0) {
    float* dst = s1 + (size_t)bh * 512 + R0 + (ln >> 4) * 4;
#pragma unroll
    for (int mr = 0; mr < 4; ++mr)
#pragma unroll
      for (int j = 0; j < 4; ++j) dst[mr * 16 + j] = rmrun[mr][j];
  }
  // colmax combine across 8 waves
  float v = cmbuf[0][t];
#pragma unroll
  for (int w = 1; w < 8; ++w) v = fmaxf(v, cmbuf[w][t]);
  s2[(size_t)bh * 512 + t] = v;
}

// ---- k2: (side,b,lq): wave h = tanh+softmax; partial readout over l-quarter
__global__ __launch_bounds__(256) void k2(const float* __restrict__ s1,
                                          const float* __restrict__ s2,
                                          const float* __restrict__ X1,
                                          const float* __restrict__ X2,
                                          float* __restrict__ out,
                                          float* __restrict__ rws4) {
  __shared__ float aL[4][512];
  __shared__ f32x4 redv[4][8][32];
  int blk = blockIdx.x;  // 512
  int side = blk >> 8, b = (blk >> 2) & 63, lq = blk & 3;
  int t = threadIdx.x, ln = t & 63, h = t >> 6;
  int bh = b * 4 + h;
  int base = ln * 8;

  const float* p = (side == 0 ? s1 : s2) + (size_t)bh * 512 + base;
  float vals[8];
  {
    float4 va = *(const float4*)p;
    float4 vb = *(const float4*)(p + 4);
    vals[0] = va.x; vals[1] = va.y; vals[2] = va.z; vals[3] = va.w;
    vals[4] = vb.x; vals[5] = vb.y; vals[6] = vb.z; vals[7] = vb.w;
  }
#pragma unroll
  for (int q = 0; q < 8; ++q) vals[q] = tanhf(vals[q]);
  float mx = vals[0];
#pragma unroll
  for (int q = 1; q < 8; ++q) mx = fmaxf(mx, vals[q]);
#pragma unroll
  for (int off = 1; off < 64; off <<= 1) mx = fmaxf(mx, __shfl_xor(mx, off));
  float s = 0.0f;
#pragma unroll
  for (int q = 0; q < 8; ++q) {
    vals[q] = expf(vals[q] - mx);
    s += vals[q];
  }
#pragma unroll
  for (int off = 1; off < 64; off <<= 1) s += __shfl_xor(s, off);
  float inv = 1.0f / s;
#pragma unroll
  for (int q = 0; q < 8; ++q) vals[q] *= inv;

  if (lq == 0) {
    int aoff = (side == 0 ? 16384 : 147456) + bh * 512 + base;
    *(float4*)(out + aoff) = make_float4(vals[0], vals[1], vals[2], vals[3]);
    *(float4*)(out + aoff + 4) = make_float4(vals[4], vals[5], vals[6], vals[7]);
  }
  *(float4*)(&aL[h][base]) = make_float4(vals[0], vals[1], vals[2], vals[3]);
  *(float4*)(&aL[h][base + 4]) = make_float4(vals[4], vals[5], vals[6], vals[7]);
  __syncthreads();

  // partial readout over l in [lq*128, +128)
  const float4* X4 = (const float4*)(side == 0 ? X1 : X2);
  int q = t & 31, lg = t >> 5;
  f32x4 av[4];
  const f32x4 fz = {0.f, 0.f, 0.f, 0.f};
#pragma unroll
  for (int hh = 0; hh < 4; ++hh) av[hh] = fz;
#pragma unroll 4
  for (int l = lq * 128 + lg; l < lq * 128 + 128; l += 8) {
    float4 xv = X4[((size_t)l * Bn + b) * 32 + q];
#pragma unroll
    for (int hh = 0; hh < 4; ++hh) {
      float w = aL[hh][l];
      av[hh][0] += w * xv.x;
      av[hh][1] += w * xv.y;
      av[hh][2] += w * xv.z;
      av[hh][3] += w * xv.w;
    }
  }
#pragma unroll
  for (int hh = 0; hh < 4; ++hh) redv[hh][lg][q] = av[hh];
  __syncthreads();
  if (t < 128) {
    int d = t;
#pragma unroll
    for (int hh = 0; hh < 4; ++hh) {
      float s2v = 0.0f;
#pragma unroll
      for (int g = 0; g < 8; ++g) s2v += ((const float*)&redv[hh][g][d >> 2])[d & 3];
      rws4[(((size_t)(side * 64 + b) * 4 + hh) * 4 + lq) * 128 + d] = s2v;
    }
  }
}

// ---- k3: combine hops (sums lq partials) ----
__global__ __launch_bounds__(128) void k3(const float* __restrict__ rws4,
                                          const float* __restrict__ Wipm,
                                          float* __restrict__ out) {
  int b = blockIdx.x, t = threadIdx.x;  // t = d
  __shared__ float r2l[4][128];
  __shared__ float tsum[2][4];
  float r1h[4], r2h[4];
#pragma unroll
  for (int h = 0; h < 4; ++h) {
    float a0 = 0.f, a1 = 0.f;
#pragma unroll
    for (int lq = 0; lq < 4; ++lq) {
      a0 += rws4[(((size_t)b * 4 + h) * 4 + lq) * 128 + t];
      a1 += rws4[(((size_t)(64 + b) * 4 + h) * 4 + lq) * 128 + t];
    }
    r1h[h] = a0;
    r2h[h] = a1;
    r2l[h][t] = a1;
  }
  __syncthreads();
  float p[4] = {0, 0, 0, 0};
  for (int e = 0; e < 128; ++e) {
    float w = Wipm[t * 128 + e];
#pragma unroll
    for (int h = 0; h < 4; ++h) p[h] += w * r2l[h][e];
  }
#pragma unroll
  for (int h = 0; h < 4; ++h) p[h] *= r1h[h];
#pragma unroll
  for (int off = 1; off < 64; off <<= 1)
#pragma unroll
    for (int h = 0; h < 4; ++h) p[h] += __shfl_xor(p[h], off);
  if ((t & 63) == 0)
#pragma unroll
    for (int h = 0; h < 4; ++h) tsum[t >> 6][h] = p[h];
  __syncthreads();
  float ad[4], mx = -3.0e38f;
#pragma unroll
  for (int h = 0; h < 4; ++h) {
    float v = tanhf(tsum[0][h] + tsum[1][h]);
    ad[h] = v;
    mx = fmaxf(mx, v);
  }
  float s = 0.0f;
#pragma unroll
  for (int h = 0; h < 4; ++h) { ad[h] = expf(ad[h] - mx); s += ad[h]; }
  float inv = 1.0f / s;
#pragma unroll
  for (int h = 0; h < 4; ++h) ad[h] *= inv;
  if (t < 4) out[278528 + b * 4 + t] = ad[t];
  float f1 = 0.0f, f2 = 0.0f;
#pragma unroll
  for (int h = 0; h < 4; ++h) { f1 += ad[h] * r1h[h]; f2 += ad[h] * r2h[h]; }
  out[b * 128 + t] = f1;
  out[8192 + b * 128 + t] = f2;
}

extern "C" void kernel_launch(void* const* d_in, const int* in_sizes, int n_in,
                              void* d_out, int out_size, void* d_ws,
                              size_t ws_size, hipStream_t stream) {
  (void)in_sizes; (void)n_in; (void)out_size; (void)ws_size;
  const float* x1 = (const float*)d_in[0];
  const float* x2 = (const float*)d_in[1];
  const int* raw1 = (const int*)d_in[2];
  const int* raw2 = (const int*)d_in[3];
  const float* wu = (const float*)d_in[4];
  const float* wipm = (const float*)d_in[5];
  float* out = (float*)d_out;
  char* w = (char*)d_ws;
  unsigned short* zimg = (unsigned short*)w;               // 64 MiB
  unsigned short* wimg = (unsigned short*)(w + 67108864);  // 512 KiB
  float* s1 = (float*)(w + 67633152);                      // 512 KiB [bh][512]
  float* s2 = (float*)(w + 68157440);                      // 512 KiB [bh][512]
  float* rws4 = (float*)(w + 68681728);                    // 1 MiB

  kw<<<32, 256, 0, stream>>>(wu, wimg);
  kz<<<1024, 256, 0, stream>>>(x2, wimg, zimg);
  k1<<<256, 512, 0, stream>>>(x1, zimg, raw1, raw2, s1, s2);
  k2<<<512, 256, 0, stream>>>(s1, s2, x1, x2, out, rws4);
  k3<<<64, 128, 0, stream>>>(rws4, wipm, out);
}